// Round 12
// baseline (610.638 us; speedup 1.0000x reference)
//
#include <hip/hip_runtime.h>
#include <math.h>

// ---------------------------------------------------------------------------
// MultiStreamCNN. R12: occupancy round.
//  - fuse: N per block 128->64 oc (acc 128->64 VGPRs) + __launch_bounds__
//    (256,3): 2 -> 3 waves/SIMD. R11 showed MfmaUtil 39% == the 2-wave TLP
//    ceiling (67k cyc MFMA/wave, both waves co-stall on per-tc B loads).
//  - conv2: tap staging phased (0-4, 5-8): LDS 73728 -> 40960 B => 4
//    blocks/CU (was 2). 2 extra barriers; A-prefetch regs survive them.
//  conv1 / wprep / det unchanged (absmax 0.0 throughout).
// ---------------------------------------------------------------------------

typedef __bf16 bf16x8 __attribute__((ext_vector_type(8)));
typedef float f32x4 __attribute__((ext_vector_type(4)));

static __device__ __forceinline__ ushort f2bf(float f) {
    unsigned u = __float_as_uint(f);
    unsigned r = (u + 0x7fffu + ((u >> 16) & 1u)) >> 16;   // RNE
    return (ushort)r;
}
static __device__ __forceinline__ float bf2f(ushort h) {
    return __uint_as_float(((unsigned)h) << 16);
}

// ---------- Kernel A: conv3x3 (3->32) + bias + relu + maxpool2 --------------
// in x: (8,3,512,512); out: NHWC bf16 hi/lo ((b*256+y)*256+x)*32 + oc.
__global__ __launch_bounds__(256) void conv1_pool(
    const float* __restrict__ x, const float* __restrict__ w,
    const float* __restrict__ bias, ushort* __restrict__ C1h,
    ushort* __restrict__ C1l)
{
    __shared__ float s[3 * 34 * 34];
    const int b = blockIdx.z;
    const int tileX = blockIdx.x, tileY = blockIdx.y;
    const int tid = threadIdx.x;
    const int tx = tid & 15, ty = tid >> 4;
    const int ih0 = tileY * 32 - 1, iw0 = tileX * 32 - 1;

    for (int i = tid; i < 3 * 34 * 34; i += 256) {
        int c = i / 1156, r = i % 1156;
        int y = r / 34, xx = r % 34;
        int ih = ih0 + y, iw = iw0 + xx;
        float v = 0.f;
        if (ih >= 0 && ih < 512 && iw >= 0 && iw < 512)
            v = x[((b * 3 + c) * 512 + ih) * 512 + iw];
        s[i] = v;
    }
    __syncthreads();

    float in[3][4][4];
#pragma unroll
    for (int c = 0; c < 3; ++c)
#pragma unroll
        for (int dy = 0; dy < 4; ++dy)
#pragma unroll
            for (int dx = 0; dx < 4; ++dx)
                in[c][dy][dx] = s[c * 1156 + (2 * ty + dy) * 34 + (2 * tx + dx)];

    const int oh = tileY * 16 + ty, ow = tileX * 16 + tx;
    __attribute__((aligned(16))) ushort hb[32];
    __attribute__((aligned(16))) ushort lb[32];
#pragma unroll
    for (int oc = 0; oc < 32; ++oc) {   // FULL unroll: hb/lb must stay in VGPRs
        const float bv = bias[oc];
        float m = -INFINITY;
#pragma unroll
        for (int py = 0; py < 2; ++py)
#pragma unroll
            for (int px = 0; px < 2; ++px) {
                float a = 0.f;
#pragma unroll
                for (int c = 0; c < 3; ++c)
#pragma unroll
                    for (int ky = 0; ky < 3; ++ky)
#pragma unroll
                        for (int kx = 0; kx < 3; ++kx)
                            a = fmaf(w[((oc * 3 + c) * 3 + ky) * 3 + kx],
                                     in[c][py + ky][px + kx], a);
                m = fmaxf(m, a);
            }
        m = fmaxf(m + bv, 0.f);
        ushort h = f2bf(m);
        hb[oc] = h;
        lb[oc] = f2bf(m - bf2f(h));
    }
    size_t base = ((size_t)((b * 256 + oh) * 256 + ow)) << 5;
    uint4* dh = (uint4*)(C1h + base);
    uint4* dl = (uint4*)(C1l + base);
#pragma unroll
    for (int k = 0; k < 4; ++k) {
        dh[k] = *(const uint4*)&hb[k * 8];
        dl[k] = *(const uint4*)&lb[k * 8];
    }
}

// ---------- Kernel B: conv2 as split-bf16 MFMA + maxpool2 -------------------
// Phased B staging (taps 0-4 then 5-8): LDS 40960 B -> 4 blocks/CU.
// Output CHUNK-PLANAR A[b][c(4)][y][x][32].
__global__ __launch_bounds__(256) void conv2_mfma(
    const ushort* __restrict__ C1h, const ushort* __restrict__ C1l,
    const float* __restrict__ w2, const float* __restrict__ bias,
    ushort* __restrict__ Ahi, ushort* __restrict__ Alo, int stream_base)
{
    __shared__ char lds[40960];            // union: B (40KB) then pool (32KB)
    ushort* Bh = (ushort*)lds;             // [ntap][oc*32+kk], up to 5 taps
    ushort* Bl = (ushort*)(lds + 20480);
    float (*pool)[32][64] = (float (*)[32][64])lds;  // [4][32][64], after taps

    const int seg = blockIdx.x, Y = blockIdx.y, b = blockIdx.z;
    const int tid = threadIdx.x, wsub = tid >> 6, lane = tid & 63;
    const int n = lane & 15, q = lane >> 4;
    const int yc = 2 * Y + (wsub & 1);              // conv row in [0,256)
    const int wx0 = seg * 128 + (wsub >> 1) * 64;   // conv x base for wave

    const uint4 zero4 = make_uint4(0u, 0u, 0u, 0u);

    // stage taps [t0, t0+ntap) of split-bf16 B. i = rel*2048 + (oc*32+kk).
    auto stageB = [&](int t0, int ntap) {
        for (int i = tid; i < ntap * 2048; i += 256) {
            int t = t0 + (i >> 11), r = i & 2047;
            float v = w2[r * 9 + t];
            ushort h = f2bf(v);
            Bh[i] = h;
            Bl[i] = f2bf(v - bf2f(h));
        }
    };

    auto loadA = [&](int t, uint4* aH, uint4* aL) {
        int ky = t / 3, kx = t - ky * 3;
        int yy = yc + ky - 1;
        bool yok = (yy >= 0) & (yy < 256);
#pragma unroll
        for (int mt = 0; mt < 4; ++mt) {
            int xp = wx0 + mt * 16 + n + kx - 1;
            bool ok = yok & (xp >= 0) & (xp < 256);
            int yyc = ok ? yy : 0, xpc = ok ? xp : 0;
            size_t off = (((size_t)((b * 256 + yyc) * 256 + xpc)) << 5) + q * 8;
            aH[mt] = ok ? *(const uint4*)(C1h + off) : zero4;
            aL[mt] = ok ? *(const uint4*)(C1l + off) : zero4;
        }
    };

    f32x4 acc[4][4];
#pragma unroll
    for (int mt = 0; mt < 4; ++mt)
#pragma unroll
        for (int nt = 0; nt < 4; ++nt) acc[mt][nt] = (f32x4){0.f, 0.f, 0.f, 0.f};

    uint4 aH[4], aL[4];
    loadA(0, aH, aL);
    stageB(0, 5);
    __syncthreads();   // phase-0 B staged

    for (int t = 0; t < 9; ++t) {
        if (t == 5) {               // phase switch: restage taps 5-8
            __syncthreads();        // all phase-0 B reads done
            stageB(5, 4);
            __syncthreads();
        }
        const int rel = (t < 5) ? t : t - 5;
        uint4 cH[4], cL[4];
#pragma unroll
        for (int mt = 0; mt < 4; ++mt) { cH[mt] = aH[mt]; cL[mt] = aL[mt]; }
        if (t + 1 < 9) loadA(t + 1, aH, aL);
        bf16x8 bh[4], bl[4];
#pragma unroll
        for (int nt = 0; nt < 4; ++nt) {
            int off = rel * 2048 + (nt * 16 + n) * 32 + q * 8;
            bh[nt] = __builtin_bit_cast(bf16x8, *(const uint4*)&Bh[off]);
            bl[nt] = __builtin_bit_cast(bf16x8, *(const uint4*)&Bl[off]);
        }
        // step-outer MFMA order (dep distance 16)
#pragma unroll
        for (int mt = 0; mt < 4; ++mt) {
            bf16x8 ah = __builtin_bit_cast(bf16x8, cH[mt]);
#pragma unroll
            for (int nt = 0; nt < 4; ++nt)
                acc[mt][nt] = __builtin_amdgcn_mfma_f32_16x16x32_bf16(ah, bh[nt], acc[mt][nt], 0, 0, 0);
        }
#pragma unroll
        for (int mt = 0; mt < 4; ++mt) {
            bf16x8 ah = __builtin_bit_cast(bf16x8, cH[mt]);
#pragma unroll
            for (int nt = 0; nt < 4; ++nt)
                acc[mt][nt] = __builtin_amdgcn_mfma_f32_16x16x32_bf16(ah, bl[nt], acc[mt][nt], 0, 0, 0);
        }
#pragma unroll
        for (int mt = 0; mt < 4; ++mt) {
            bf16x8 al = __builtin_bit_cast(bf16x8, cL[mt]);
#pragma unroll
            for (int nt = 0; nt < 4; ++nt)
                acc[mt][nt] = __builtin_amdgcn_mfma_f32_16x16x32_bf16(al, bh[nt], acc[mt][nt], 0, 0, 0);
        }
    }

    __syncthreads();   // all B reads done; safe to overwrite with pool

#pragma unroll
    for (int mt = 0; mt < 4; ++mt)
#pragma unroll
        for (int nt = 0; nt < 4; ++nt) {
            int oc = nt * 16 + n;
            int plx = mt * 8 + q * 2;
            pool[wsub][plx][oc]     = fmaxf(acc[mt][nt][0], acc[mt][nt][1]);
            pool[wsub][plx + 1][oc] = fmaxf(acc[mt][nt][2], acc[mt][nt][3]);
        }
    __syncthreads();

    {
        int plx = tid >> 2, ocq = tid & 3;
        int wp = plx >> 5, pl = plx & 31;
        __attribute__((aligned(16))) ushort hb[16], lb[16];
#pragma unroll
        for (int e = 0; e < 16; ++e) {
            int oc = ocq * 16 + e;
            float v = fmaxf(pool[wp * 2][pl][oc], pool[wp * 2 + 1][pl][oc]);
            v = fmaxf(v + bias[oc], 0.f);
            ushort h = f2bf(v);
            hb[e] = h;
            lb[e] = f2bf(v - bf2f(h));
        }
        int gx = seg * 64 + plx;
        // chunk-planar write: global ch = stream_base + ocq*16
        int cpl = (stream_base >> 5) + (ocq >> 1);
        int cho = (ocq & 1) * 16;
        size_t base = (((size_t)(((b * 4 + cpl) * 128 + Y) * 128 + gx)) << 5) + cho;
        uint4* dh = (uint4*)(Ahi + base);
        uint4* dl = (uint4*)(Alo + base);
        dh[0] = *(const uint4*)&hb[0];
        dh[1] = *(const uint4*)&hb[8];
        dl[0] = *(const uint4*)&lb[0];
        dl[1] = *(const uint4*)&lb[8];
    }
}

// ---------- wprep: fuse_w fp32 -> fragment-ordered bf16 hi/lo ---------------
// CHUNK-MAJOR: Wf[c][t][oc][kk] = W[oc][ic=c*32+kk][ky=t/3][kx=t%3]
__global__ __launch_bounds__(256) void wprep(
    const float* __restrict__ fw, ushort* __restrict__ Whi,
    ushort* __restrict__ Wlo)
{
    int idx = blockIdx.x * 256 + threadIdx.x;
    if (idx >= 147456) return;
    int kk = idx & 31;
    int oc = (idx >> 5) & 127;
    int ct = idx >> 12;           // 0..35 = c*9 + t
    int c = ct / 9, t = ct - c * 9;
    int ic = c * 32 + kk;
    int ky = t / 3, kx = t - ky * 3;
    float v = fw[((oc * 128 + ic) * 3 + ky) * 3 + kx];
    ushort h = f2bf(v);
    Whi[idx] = h;
    Wlo[idx] = f2bf(v - bf2f(h));
}

// ---------- Kernel C: fuse conv via split-bf16 MFMA + relu + global mean ----
// Block: 256 px x 64 oc (oc-half per blockIdx.z); wave = 64 px x 64 oc.
// acc = 64 VGPRs -> 3 waves/SIMD (was 2 with 128-oc blocks).
__global__ __launch_bounds__(256, 3) void fuse_mfma(
    const ushort* __restrict__ Ahi, const ushort* __restrict__ Alo,
    const ushort* __restrict__ Whi, const ushort* __restrict__ Wlo,
    const float* __restrict__ bias, float* __restrict__ featsum)
{
    __shared__ float partial[4][64];
    const int b = blockIdx.x, ypair = blockIdx.y, oh = blockIdx.z;
    const int tid = threadIdx.x, wsub = tid >> 6, lane = tid & 63;
    const int n = lane & 15, q = lane >> 4;
    const int y = ypair * 2 + (wsub >> 1);       // conv row for this wave
    const int xbase = (wsub & 1) * 64;           // wave covers x [xbase,xbase+64)

    f32x4 acc[4][4];
#pragma unroll
    for (int mt = 0; mt < 4; ++mt)
#pragma unroll
        for (int g = 0; g < 4; ++g) acc[mt][g] = (f32x4){0.f, 0.f, 0.f, 0.f};

    const uint4 zero4 = make_uint4(0u, 0u, 0u, 0u);

    auto loadA = [&](int tc, uint4* ohh, uint4* oll) {
        int c = tc / 9, t = tc - c * 9;   // chunk-major decode
        int ky = t / 3, kx = t - ky * 3;
        int yy = y + ky - 1;
        bool yok = (yy >= 0) & (yy < 128);
#pragma unroll
        for (int mt = 0; mt < 4; ++mt) {
            int xp = xbase + mt * 16 + n + kx - 1;
            bool ok = yok & (xp >= 0) & (xp < 128);
            int yyc = ok ? yy : 0, xpc = ok ? xp : 0;
            size_t aoff = (((size_t)(((b * 4 + c) * 128 + yyc) * 128 + xpc)) << 5) + q * 8;
            ohh[mt] = ok ? *(const uint4*)(Ahi + aoff) : zero4;
            oll[mt] = ok ? *(const uint4*)(Alo + aoff) : zero4;
        }
    };

    uint4 pAh[4], pAl[4];
    loadA(0, pAh, pAl);

    // lane-fixed part of the B-fragment address (this block's oc half)
    const int boff = (oh * 64 + n) * 32 + q * 8;

    for (int tc = 0; tc < 36; ++tc) {
        uint4 cAh[4], cAl[4];
#pragma unroll
        for (int mt = 0; mt < 4; ++mt) { cAh[mt] = pAh[mt]; cAl[mt] = pAl[mt]; }
        if (tc + 1 < 36) loadA(tc + 1, pAh, pAl);
        const ushort* bhp = Whi + tc * 4096 + boff;
        const ushort* blp = Wlo + tc * 4096 + boff;
#pragma unroll
        for (int g = 0; g < 4; ++g) {
            bf16x8 bh = __builtin_bit_cast(bf16x8, *(const uint4*)(bhp + g * 512));
            bf16x8 bl = __builtin_bit_cast(bf16x8, *(const uint4*)(blp + g * 512));
#pragma unroll
            for (int mt = 0; mt < 4; ++mt) {
                bf16x8 ah = __builtin_bit_cast(bf16x8, cAh[mt]);
                acc[mt][g] = __builtin_amdgcn_mfma_f32_16x16x32_bf16(ah, bh, acc[mt][g], 0, 0, 0);
            }
#pragma unroll
            for (int mt = 0; mt < 4; ++mt) {
                bf16x8 ah = __builtin_bit_cast(bf16x8, cAh[mt]);
                acc[mt][g] = __builtin_amdgcn_mfma_f32_16x16x32_bf16(ah, bl, acc[mt][g], 0, 0, 0);
            }
#pragma unroll
            for (int mt = 0; mt < 4; ++mt) {
                bf16x8 al = __builtin_bit_cast(bf16x8, cAl[mt]);
                acc[mt][g] = __builtin_amdgcn_mfma_f32_16x16x32_bf16(al, bh, acc[mt][g], 0, 0, 0);
            }
        }
    }

    // Epilogue: lane (q,n) of tile (mt,g) holds D[px = q*4+r][oc = oh*64+g*16+n].
#pragma unroll
    for (int g = 0; g < 4; ++g) {
        float bv = bias[oh * 64 + g * 16 + n];
        float v = 0.f;
#pragma unroll
        for (int mt = 0; mt < 4; ++mt)
#pragma unroll
            for (int r = 0; r < 4; ++r) v += fmaxf(acc[mt][g][r] + bv, 0.f);
        v += __shfl_xor(v, 16);
        v += __shfl_xor(v, 32);
        if (lane < 16) partial[wsub][g * 16 + lane] = v;
    }
    __syncthreads();
    if (tid < 64) {
        float v = partial[0][tid] + partial[1][tid] + partial[2][tid] + partial[3][tid];
        atomicAdd(&featsum[b * 128 + oh * 64 + tid], v);
    }
}

// ---------- Kernel D: det head + sigmoid + NMS + outputs --------------------
__global__ void det_nms(const float* __restrict__ featsum,
                        const float* __restrict__ dw, const float* __restrict__ db,
                        float* __restrict__ out)
{
    const int b = threadIdx.x;
    if (b >= 8) return;
    const float inv = 1.0f / 16384.0f;

    float p[18];
    for (int j = 0; j < 18; ++j) {
        float a = db[j];
        const float* wp = &dw[j * 128];
        const float* f = &featsum[b * 128];
        for (int c = 0; c < 128; ++c) a = fmaf(wp[c], f[c] * inv, a);
        p[j] = a;
    }
    for (int a = 0; a < 3; ++a)
        for (int e = 0; e < 6; ++e) out[b * 18 + a * 6 + e] = p[a * 6 + e];

    float bx[3][4], sc[3];
    bool ck[3];
    for (int a = 0; a < 3; ++a) {
        for (int k = 0; k < 4; ++k) {
            bx[a][k] = p[a * 6 + k];
            out[144 + b * 12 + a * 4 + k] = bx[a][k];
        }
        float sg = 1.f / (1.f + expf(-p[a * 6 + 4]));
        sc[a] = sg;
        ck[a] = sg > 0.5f;
        out[240 + b * 3 + a] = sg;
    }

    float key[3];
    int order[3];
    bool used[3] = {false, false, false};
    for (int a = 0; a < 3; ++a) key[a] = ck[a] ? sc[a] : -INFINITY;
    for (int i = 0; i < 3; ++i) {
        int best = -1;
        float bk = 0.f;
        for (int a = 0; a < 3; ++a) {
            if (used[a]) continue;
            if (best < 0 || key[a] > bk) { best = a; bk = key[a]; }
        }
        order[i] = best;
        used[best] = true;
    }

    float X1[3], Y1[3], X2[3], Y2[3], AR[3];
    for (int i = 0; i < 3; ++i) {
        int o = order[i];
        X1[i] = bx[o][0]; Y1[i] = bx[o][1];
        X2[i] = bx[o][2]; Y2[i] = bx[o][3];
        AR[i] = (X2[i] - X1[i]) * (Y2[i] - Y1[i]);
    }
    bool suppressed[3] = {false, false, false}, keep_s[3];
    for (int i = 0; i < 3; ++i) {
        bool valid = !suppressed[i];
        keep_s[i] = valid;
        if (valid) {
            for (int j = i + 1; j < 3; ++j) {
                float ix1 = fmaxf(X1[i], X1[j]), iy1 = fmaxf(Y1[i], Y1[j]);
                float ix2 = fminf(X2[i], X2[j]), iy2 = fminf(Y2[i], Y2[j]);
                float inter = fmaxf(ix2 - ix1, 0.f) * fmaxf(iy2 - iy1, 0.f);
                float iou = inter / (AR[i] + AR[j] - inter);
                if (iou > 0.5f) suppressed[j] = true;
            }
        }
    }
    bool keep[3];
    for (int i = 0; i < 3; ++i) keep[order[i]] = keep_s[i];
    for (int a = 0; a < 3; ++a)
        out[264 + b * 3 + a] = (keep[a] && ck[a]) ? 1.f : 0.f;
}

__global__ void zero_feat(float* __restrict__ p)
{
    int i = blockIdx.x * 256 + threadIdx.x;
    if (i < 1024) p[i] = 0.f;
}

// ---------------------------------------------------------------------------
extern "C" void kernel_launch(void* const* d_in, const int* in_sizes, int n_in,
                              void* d_out, int out_size, void* d_ws, size_t ws_size,
                              hipStream_t stream)
{
    const float* x      = (const float*)d_in[0];
    const float* rgb_w1 = (const float*)d_in[1];
    const float* rgb_b1 = (const float*)d_in[2];
    const float* rgb_w2 = (const float*)d_in[3];
    const float* rgb_b2 = (const float*)d_in[4];
    const float* ir_w1  = (const float*)d_in[5];
    const float* ir_b1  = (const float*)d_in[6];
    const float* ir_w2  = (const float*)d_in[7];
    const float* ir_b2  = (const float*)d_in[8];
    const float* fuse_w = (const float*)d_in[9];
    const float* fuse_b = (const float*)d_in[10];
    const float* det_w  = (const float*)d_in[11];
    const float* det_b  = (const float*)d_in[12];
    float* out = (float*)d_out;

    char* ws = (char*)d_ws;
    ushort* C1h  = (ushort*)(ws);                         // 33,554,432 B
    ushort* C1l  = (ushort*)(ws + 33554432);              // 33,554,432 B
    ushort* Whi  = (ushort*)(ws);                         // 294,912 B (post-conv2)
    ushort* Wlo  = (ushort*)(ws + 294912);                // 294,912 B
    float*  feat = (float*)(ws + 589824);                 // 4,096 B
    ushort* Ahi  = (ushort*)(ws + 67108864);              // 33,554,432 B
    ushort* Alo  = (ushort*)(ws + 100663296);             // 33,554,432 B

    dim3 blk(256);
    hipLaunchKernelGGL(conv1_pool, dim3(16, 16, 8), blk, 0, stream, x, rgb_w1, rgb_b1, C1h, C1l);
    hipLaunchKernelGGL(conv2_mfma, dim3(2, 128, 8), blk, 0, stream, C1h, C1l, rgb_w2, rgb_b2, Ahi, Alo, 0);
    hipLaunchKernelGGL(conv1_pool, dim3(16, 16, 8), blk, 0, stream, x, ir_w1, ir_b1, C1h, C1l);
    hipLaunchKernelGGL(conv2_mfma, dim3(2, 128, 8), blk, 0, stream, C1h, C1l, ir_w2, ir_b2, Ahi, Alo, 64);
    hipLaunchKernelGGL(wprep, dim3(576), blk, 0, stream, fuse_w, Whi, Wlo);
    hipLaunchKernelGGL(zero_feat, dim3(4), blk, 0, stream, feat);
    hipLaunchKernelGGL(fuse_mfma, dim3(8, 64, 2), blk, 0, stream, Ahi, Alo, Whi, Wlo, fuse_b, feat);
    hipLaunchKernelGGL(det_nms, dim3(1), dim3(64), 0, stream, feat, det_w, det_b, out);
}

// Round 13
// 544.562 us; speedup vs baseline: 1.1213x; 1.1213x over previous
//
#include <hip/hip_runtime.h>
#include <math.h>

// ---------------------------------------------------------------------------
// MultiStreamCNN. R13: revert R12's fuse oc-split (regression: worse
// MFMA:load ratio, no occupancy gain). Back to R11 shape (256px x 128oc,
// 2 blocks/CU) + NEW: rolling 4-deep register prefetch of B. B's address is
// flat in s = tc*8+g (W + boff + s*512); consume slot g&3, prefetch s+4
// (~230cyc ahead >= L2 latency). W buffers padded by 4 steps (4KB) so tail
// prefetches hit valid memory. conv2 keeps R12's phased staging.
// ---------------------------------------------------------------------------

typedef __bf16 bf16x8 __attribute__((ext_vector_type(8)));
typedef float f32x4 __attribute__((ext_vector_type(4)));

static __device__ __forceinline__ ushort f2bf(float f) {
    unsigned u = __float_as_uint(f);
    unsigned r = (u + 0x7fffu + ((u >> 16) & 1u)) >> 16;   // RNE
    return (ushort)r;
}
static __device__ __forceinline__ float bf2f(ushort h) {
    return __uint_as_float(((unsigned)h) << 16);
}

// ---------- Kernel A: conv3x3 (3->32) + bias + relu + maxpool2 --------------
__global__ __launch_bounds__(256) void conv1_pool(
    const float* __restrict__ x, const float* __restrict__ w,
    const float* __restrict__ bias, ushort* __restrict__ C1h,
    ushort* __restrict__ C1l)
{
    __shared__ float s[3 * 34 * 34];
    const int b = blockIdx.z;
    const int tileX = blockIdx.x, tileY = blockIdx.y;
    const int tid = threadIdx.x;
    const int tx = tid & 15, ty = tid >> 4;
    const int ih0 = tileY * 32 - 1, iw0 = tileX * 32 - 1;

    for (int i = tid; i < 3 * 34 * 34; i += 256) {
        int c = i / 1156, r = i % 1156;
        int y = r / 34, xx = r % 34;
        int ih = ih0 + y, iw = iw0 + xx;
        float v = 0.f;
        if (ih >= 0 && ih < 512 && iw >= 0 && iw < 512)
            v = x[((b * 3 + c) * 512 + ih) * 512 + iw];
        s[i] = v;
    }
    __syncthreads();

    float in[3][4][4];
#pragma unroll
    for (int c = 0; c < 3; ++c)
#pragma unroll
        for (int dy = 0; dy < 4; ++dy)
#pragma unroll
            for (int dx = 0; dx < 4; ++dx)
                in[c][dy][dx] = s[c * 1156 + (2 * ty + dy) * 34 + (2 * tx + dx)];

    const int oh = tileY * 16 + ty, ow = tileX * 16 + tx;
    __attribute__((aligned(16))) ushort hb[32];
    __attribute__((aligned(16))) ushort lb[32];
#pragma unroll
    for (int oc = 0; oc < 32; ++oc) {   // FULL unroll: hb/lb must stay in VGPRs
        const float bv = bias[oc];
        float m = -INFINITY;
#pragma unroll
        for (int py = 0; py < 2; ++py)
#pragma unroll
            for (int px = 0; px < 2; ++px) {
                float a = 0.f;
#pragma unroll
                for (int c = 0; c < 3; ++c)
#pragma unroll
                    for (int ky = 0; ky < 3; ++ky)
#pragma unroll
                        for (int kx = 0; kx < 3; ++kx)
                            a = fmaf(w[((oc * 3 + c) * 3 + ky) * 3 + kx],
                                     in[c][py + ky][px + kx], a);
                m = fmaxf(m, a);
            }
        m = fmaxf(m + bv, 0.f);
        ushort h = f2bf(m);
        hb[oc] = h;
        lb[oc] = f2bf(m - bf2f(h));
    }
    size_t base = ((size_t)((b * 256 + oh) * 256 + ow)) << 5;
    uint4* dh = (uint4*)(C1h + base);
    uint4* dl = (uint4*)(C1l + base);
#pragma unroll
    for (int k = 0; k < 4; ++k) {
        dh[k] = *(const uint4*)&hb[k * 8];
        dl[k] = *(const uint4*)&lb[k * 8];
    }
}

// ---------- Kernel B: conv2 as split-bf16 MFMA + maxpool2 -------------------
// Phased B staging (taps 0-4 then 5-8): LDS 40960 B -> 4 blocks/CU.
// Output CHUNK-PLANAR A[b][c(4)][y][x][32].
__global__ __launch_bounds__(256) void conv2_mfma(
    const ushort* __restrict__ C1h, const ushort* __restrict__ C1l,
    const float* __restrict__ w2, const float* __restrict__ bias,
    ushort* __restrict__ Ahi, ushort* __restrict__ Alo, int stream_base)
{
    __shared__ char lds[40960];            // union: B (40KB) then pool (32KB)
    ushort* Bh = (ushort*)lds;             // [ntap][oc*32+kk], up to 5 taps
    ushort* Bl = (ushort*)(lds + 20480);
    float (*pool)[32][64] = (float (*)[32][64])lds;  // [4][32][64], after taps

    const int seg = blockIdx.x, Y = blockIdx.y, b = blockIdx.z;
    const int tid = threadIdx.x, wsub = tid >> 6, lane = tid & 63;
    const int n = lane & 15, q = lane >> 4;
    const int yc = 2 * Y + (wsub & 1);              // conv row in [0,256)
    const int wx0 = seg * 128 + (wsub >> 1) * 64;   // conv x base for wave

    const uint4 zero4 = make_uint4(0u, 0u, 0u, 0u);

    auto stageB = [&](int t0, int ntap) {
        for (int i = tid; i < ntap * 2048; i += 256) {
            int t = t0 + (i >> 11), r = i & 2047;
            float v = w2[r * 9 + t];
            ushort h = f2bf(v);
            Bh[i] = h;
            Bl[i] = f2bf(v - bf2f(h));
        }
    };

    auto loadA = [&](int t, uint4* aH, uint4* aL) {
        int ky = t / 3, kx = t - ky * 3;
        int yy = yc + ky - 1;
        bool yok = (yy >= 0) & (yy < 256);
#pragma unroll
        for (int mt = 0; mt < 4; ++mt) {
            int xp = wx0 + mt * 16 + n + kx - 1;
            bool ok = yok & (xp >= 0) & (xp < 256);
            int yyc = ok ? yy : 0, xpc = ok ? xp : 0;
            size_t off = (((size_t)((b * 256 + yyc) * 256 + xpc)) << 5) + q * 8;
            aH[mt] = ok ? *(const uint4*)(C1h + off) : zero4;
            aL[mt] = ok ? *(const uint4*)(C1l + off) : zero4;
        }
    };

    f32x4 acc[4][4];
#pragma unroll
    for (int mt = 0; mt < 4; ++mt)
#pragma unroll
        for (int nt = 0; nt < 4; ++nt) acc[mt][nt] = (f32x4){0.f, 0.f, 0.f, 0.f};

    uint4 aH[4], aL[4];
    loadA(0, aH, aL);
    stageB(0, 5);
    __syncthreads();   // phase-0 B staged

    for (int t = 0; t < 9; ++t) {
        if (t == 5) {               // phase switch: restage taps 5-8
            __syncthreads();        // all phase-0 B reads done
            stageB(5, 4);
            __syncthreads();
        }
        const int rel = (t < 5) ? t : t - 5;
        uint4 cH[4], cL[4];
#pragma unroll
        for (int mt = 0; mt < 4; ++mt) { cH[mt] = aH[mt]; cL[mt] = aL[mt]; }
        if (t + 1 < 9) loadA(t + 1, aH, aL);
        bf16x8 bh[4], bl[4];
#pragma unroll
        for (int nt = 0; nt < 4; ++nt) {
            int off = rel * 2048 + (nt * 16 + n) * 32 + q * 8;
            bh[nt] = __builtin_bit_cast(bf16x8, *(const uint4*)&Bh[off]);
            bl[nt] = __builtin_bit_cast(bf16x8, *(const uint4*)&Bl[off]);
        }
        // step-outer MFMA order (dep distance 16)
#pragma unroll
        for (int mt = 0; mt < 4; ++mt) {
            bf16x8 ah = __builtin_bit_cast(bf16x8, cH[mt]);
#pragma unroll
            for (int nt = 0; nt < 4; ++nt)
                acc[mt][nt] = __builtin_amdgcn_mfma_f32_16x16x32_bf16(ah, bh[nt], acc[mt][nt], 0, 0, 0);
        }
#pragma unroll
        for (int mt = 0; mt < 4; ++mt) {
            bf16x8 ah = __builtin_bit_cast(bf16x8, cH[mt]);
#pragma unroll
            for (int nt = 0; nt < 4; ++nt)
                acc[mt][nt] = __builtin_amdgcn_mfma_f32_16x16x32_bf16(ah, bl[nt], acc[mt][nt], 0, 0, 0);
        }
#pragma unroll
        for (int mt = 0; mt < 4; ++mt) {
            bf16x8 al = __builtin_bit_cast(bf16x8, cL[mt]);
#pragma unroll
            for (int nt = 0; nt < 4; ++nt)
                acc[mt][nt] = __builtin_amdgcn_mfma_f32_16x16x32_bf16(al, bh[nt], acc[mt][nt], 0, 0, 0);
        }
    }

    __syncthreads();   // all B reads done; safe to overwrite with pool

#pragma unroll
    for (int mt = 0; mt < 4; ++mt)
#pragma unroll
        for (int nt = 0; nt < 4; ++nt) {
            int oc = nt * 16 + n;
            int plx = mt * 8 + q * 2;
            pool[wsub][plx][oc]     = fmaxf(acc[mt][nt][0], acc[mt][nt][1]);
            pool[wsub][plx + 1][oc] = fmaxf(acc[mt][nt][2], acc[mt][nt][3]);
        }
    __syncthreads();

    {
        int plx = tid >> 2, ocq = tid & 3;
        int wp = plx >> 5, pl = plx & 31;
        __attribute__((aligned(16))) ushort hb[16], lb[16];
#pragma unroll
        for (int e = 0; e < 16; ++e) {
            int oc = ocq * 16 + e;
            float v = fmaxf(pool[wp * 2][pl][oc], pool[wp * 2 + 1][pl][oc]);
            v = fmaxf(v + bias[oc], 0.f);
            ushort h = f2bf(v);
            hb[e] = h;
            lb[e] = f2bf(v - bf2f(h));
        }
        int gx = seg * 64 + plx;
        int cpl = (stream_base >> 5) + (ocq >> 1);
        int cho = (ocq & 1) * 16;
        size_t base = (((size_t)(((b * 4 + cpl) * 128 + Y) * 128 + gx)) << 5) + cho;
        uint4* dh = (uint4*)(Ahi + base);
        uint4* dl = (uint4*)(Alo + base);
        dh[0] = *(const uint4*)&hb[0];
        dh[1] = *(const uint4*)&hb[8];
        dl[0] = *(const uint4*)&lb[0];
        dl[1] = *(const uint4*)&lb[8];
    }
}

// ---------- wprep: fuse_w fp32 -> fragment-ordered bf16 hi/lo ---------------
// CHUNK-MAJOR: Wf[c][t][oc][kk] = W[oc][ic=c*32+kk][ky=t/3][kx=t%3]
__global__ __launch_bounds__(256) void wprep(
    const float* __restrict__ fw, ushort* __restrict__ Whi,
    ushort* __restrict__ Wlo)
{
    int idx = blockIdx.x * 256 + threadIdx.x;
    if (idx >= 147456) return;
    int kk = idx & 31;
    int oc = (idx >> 5) & 127;
    int ct = idx >> 12;           // 0..35 = c*9 + t
    int c = ct / 9, t = ct - c * 9;
    int ic = c * 32 + kk;
    int ky = t / 3, kx = t - ky * 3;
    float v = fw[((oc * 128 + ic) * 3 + ky) * 3 + kx];
    ushort h = f2bf(v);
    Whi[idx] = h;
    Wlo[idx] = f2bf(v - bf2f(h));
}

// ---------- Kernel C: fuse conv via split-bf16 MFMA + relu + global mean ----
// R11 shape (256px x 128oc, wave = 64px x 128oc) + rolling 4-deep register
// prefetch of B (flat step s = tc*8+g, addr = W + boff + s*512).
__global__ __launch_bounds__(256, 2) void fuse_mfma(
    const ushort* __restrict__ Ahi, const ushort* __restrict__ Alo,
    const ushort* __restrict__ Whi, const ushort* __restrict__ Wlo,
    const float* __restrict__ bias, float* __restrict__ featsum)
{
    __shared__ float partial[4][128];
    const int b = blockIdx.x, ypair = blockIdx.y;
    const int tid = threadIdx.x, wsub = tid >> 6, lane = tid & 63;
    const int n = lane & 15, q = lane >> 4;
    const int y = ypair * 2 + (wsub >> 1);       // conv row for this wave
    const int xbase = (wsub & 1) * 64;           // wave covers x [xbase,xbase+64)

    f32x4 acc[4][8];
#pragma unroll
    for (int mt = 0; mt < 4; ++mt)
#pragma unroll
        for (int g = 0; g < 8; ++g) acc[mt][g] = (f32x4){0.f, 0.f, 0.f, 0.f};

    const uint4 zero4 = make_uint4(0u, 0u, 0u, 0u);

    auto loadA = [&](int tc, uint4* oh, uint4* ol) {
        int c = tc / 9, t = tc - c * 9;   // chunk-major decode
        int ky = t / 3, kx = t - ky * 3;
        int yy = y + ky - 1;
        bool yok = (yy >= 0) & (yy < 128);
#pragma unroll
        for (int mt = 0; mt < 4; ++mt) {
            int xp = xbase + mt * 16 + n + kx - 1;
            bool ok = yok & (xp >= 0) & (xp < 128);
            int yyc = ok ? yy : 0, xpc = ok ? xp : 0;
            size_t aoff = (((size_t)(((b * 4 + c) * 128 + yyc) * 128 + xpc)) << 5) + q * 8;
            oh[mt] = ok ? *(const uint4*)(Ahi + aoff) : zero4;
            ol[mt] = ok ? *(const uint4*)(Alo + aoff) : zero4;
        }
    };

    uint4 pAh[4], pAl[4];
    loadA(0, pAh, pAl);

    // lane-fixed B base; step address = base + s*512, s = tc*8+g
    const ushort* WhiB = Whi + n * 32 + q * 8;
    const ushort* WloB = Wlo + n * 32 + q * 8;

    // rolling 4-deep B prefetch buffer
    uint4 nBh[4], nBl[4];
#pragma unroll
    for (int j = 0; j < 4; ++j) {
        nBh[j] = *(const uint4*)(WhiB + j * 512);
        nBl[j] = *(const uint4*)(WloB + j * 512);
    }

    for (int tc = 0; tc < 36; ++tc) {
        uint4 cAh[4], cAl[4];
#pragma unroll
        for (int mt = 0; mt < 4; ++mt) { cAh[mt] = pAh[mt]; cAl[mt] = pAl[mt]; }
        if (tc + 1 < 36) loadA(tc + 1, pAh, pAl);
#pragma unroll
        for (int g = 0; g < 8; ++g) {
            const int slot = g & 3;
            bf16x8 bh = __builtin_bit_cast(bf16x8, nBh[slot]);
            bf16x8 bl = __builtin_bit_cast(bf16x8, nBl[slot]);
            // prefetch step s+4 (tail reads 4 padded never-consumed steps)
            {
                size_t off = (size_t)(tc * 8 + g + 4) * 512;
                nBh[slot] = *(const uint4*)(WhiB + off);
                nBl[slot] = *(const uint4*)(WloB + off);
            }
#pragma unroll
            for (int mt = 0; mt < 4; ++mt) {
                bf16x8 ah = __builtin_bit_cast(bf16x8, cAh[mt]);
                acc[mt][g] = __builtin_amdgcn_mfma_f32_16x16x32_bf16(ah, bh, acc[mt][g], 0, 0, 0);
            }
#pragma unroll
            for (int mt = 0; mt < 4; ++mt) {
                bf16x8 ah = __builtin_bit_cast(bf16x8, cAh[mt]);
                acc[mt][g] = __builtin_amdgcn_mfma_f32_16x16x32_bf16(ah, bl, acc[mt][g], 0, 0, 0);
            }
#pragma unroll
            for (int mt = 0; mt < 4; ++mt) {
                bf16x8 al = __builtin_bit_cast(bf16x8, cAl[mt]);
                acc[mt][g] = __builtin_amdgcn_mfma_f32_16x16x32_bf16(al, bh, acc[mt][g], 0, 0, 0);
            }
        }
    }

    // Epilogue: lane (q,n) of tile (mt,g) holds D[px = q*4+r][oc = g*16+n].
#pragma unroll
    for (int g = 0; g < 8; ++g) {
        float bv = bias[g * 16 + n];
        float v = 0.f;
#pragma unroll
        for (int mt = 0; mt < 4; ++mt)
#pragma unroll
            for (int r = 0; r < 4; ++r) v += fmaxf(acc[mt][g][r] + bv, 0.f);
        v += __shfl_xor(v, 16);
        v += __shfl_xor(v, 32);
        if (lane < 16) partial[wsub][g * 16 + lane] = v;
    }
    __syncthreads();
    if (tid < 128) {
        float v = partial[0][tid] + partial[1][tid] + partial[2][tid] + partial[3][tid];
        atomicAdd(&featsum[b * 128 + tid], v);
    }
}

// ---------- Kernel D: det head + sigmoid + NMS + outputs --------------------
__global__ void det_nms(const float* __restrict__ featsum,
                        const float* __restrict__ dw, const float* __restrict__ db,
                        float* __restrict__ out)
{
    const int b = threadIdx.x;
    if (b >= 8) return;
    const float inv = 1.0f / 16384.0f;

    float p[18];
    for (int j = 0; j < 18; ++j) {
        float a = db[j];
        const float* wp = &dw[j * 128];
        const float* f = &featsum[b * 128];
        for (int c = 0; c < 128; ++c) a = fmaf(wp[c], f[c] * inv, a);
        p[j] = a;
    }
    for (int a = 0; a < 3; ++a)
        for (int e = 0; e < 6; ++e) out[b * 18 + a * 6 + e] = p[a * 6 + e];

    float bx[3][4], sc[3];
    bool ck[3];
    for (int a = 0; a < 3; ++a) {
        for (int k = 0; k < 4; ++k) {
            bx[a][k] = p[a * 6 + k];
            out[144 + b * 12 + a * 4 + k] = bx[a][k];
        }
        float sg = 1.f / (1.f + expf(-p[a * 6 + 4]));
        sc[a] = sg;
        ck[a] = sg > 0.5f;
        out[240 + b * 3 + a] = sg;
    }

    float key[3];
    int order[3];
    bool used[3] = {false, false, false};
    for (int a = 0; a < 3; ++a) key[a] = ck[a] ? sc[a] : -INFINITY;
    for (int i = 0; i < 3; ++i) {
        int best = -1;
        float bk = 0.f;
        for (int a = 0; a < 3; ++a) {
            if (used[a]) continue;
            if (best < 0 || key[a] > bk) { best = a; bk = key[a]; }
        }
        order[i] = best;
        used[best] = true;
    }

    float X1[3], Y1[3], X2[3], Y2[3], AR[3];
    for (int i = 0; i < 3; ++i) {
        int o = order[i];
        X1[i] = bx[o][0]; Y1[i] = bx[o][1];
        X2[i] = bx[o][2]; Y2[i] = bx[o][3];
        AR[i] = (X2[i] - X1[i]) * (Y2[i] - Y1[i]);
    }
    bool suppressed[3] = {false, false, false}, keep_s[3];
    for (int i = 0; i < 3; ++i) {
        bool valid = !suppressed[i];
        keep_s[i] = valid;
        if (valid) {
            for (int j = i + 1; j < 3; ++j) {
                float ix1 = fmaxf(X1[i], X1[j]), iy1 = fmaxf(Y1[i], Y1[j]);
                float ix2 = fminf(X2[i], X2[j]), iy2 = fminf(Y2[i], Y2[j]);
                float inter = fmaxf(ix2 - ix1, 0.f) * fmaxf(iy2 - iy1, 0.f);
                float iou = inter / (AR[i] + AR[j] - inter);
                if (iou > 0.5f) suppressed[j] = true;
            }
        }
    }
    bool keep[3];
    for (int i = 0; i < 3; ++i) keep[order[i]] = keep_s[i];
    for (int a = 0; a < 3; ++a)
        out[264 + b * 3 + a] = (keep[a] && ck[a]) ? 1.f : 0.f;
}

__global__ void zero_feat(float* __restrict__ p)
{
    int i = blockIdx.x * 256 + threadIdx.x;
    if (i < 1024) p[i] = 0.f;
}

// ---------------------------------------------------------------------------
extern "C" void kernel_launch(void* const* d_in, const int* in_sizes, int n_in,
                              void* d_out, int out_size, void* d_ws, size_t ws_size,
                              hipStream_t stream)
{
    const float* x      = (const float*)d_in[0];
    const float* rgb_w1 = (const float*)d_in[1];
    const float* rgb_b1 = (const float*)d_in[2];
    const float* rgb_w2 = (const float*)d_in[3];
    const float* rgb_b2 = (const float*)d_in[4];
    const float* ir_w1  = (const float*)d_in[5];
    const float* ir_b1  = (const float*)d_in[6];
    const float* ir_w2  = (const float*)d_in[7];
    const float* ir_b2  = (const float*)d_in[8];
    const float* fuse_w = (const float*)d_in[9];
    const float* fuse_b = (const float*)d_in[10];
    const float* det_w  = (const float*)d_in[11];
    const float* det_b  = (const float*)d_in[12];
    float* out = (float*)d_out;

    char* ws = (char*)d_ws;
    ushort* C1h  = (ushort*)(ws);                         // 33,554,432 B
    ushort* C1l  = (ushort*)(ws + 33554432);              // 33,554,432 B
    // post-conv2 reuse of the C1 region (W padded by 4 flat steps = 4096 B):
    ushort* Whi  = (ushort*)(ws);                         // 299,008 B span
    ushort* Wlo  = (ushort*)(ws + 299008);                // 299,008 B span
    float*  feat = (float*)(ws + 598016);                 // 4,096 B
    ushort* Ahi  = (ushort*)(ws + 67108864);              // 33,554,432 B
    ushort* Alo  = (ushort*)(ws + 100663296);             // 33,554,432 B

    dim3 blk(256);
    hipLaunchKernelGGL(conv1_pool, dim3(16, 16, 8), blk, 0, stream, x, rgb_w1, rgb_b1, C1h, C1l);
    hipLaunchKernelGGL(conv2_mfma, dim3(2, 128, 8), blk, 0, stream, C1h, C1l, rgb_w2, rgb_b2, Ahi, Alo, 0);
    hipLaunchKernelGGL(conv1_pool, dim3(16, 16, 8), blk, 0, stream, x, ir_w1, ir_b1, C1h, C1l);
    hipLaunchKernelGGL(conv2_mfma, dim3(2, 128, 8), blk, 0, stream, C1h, C1l, ir_w2, ir_b2, Ahi, Alo, 64);
    hipLaunchKernelGGL(wprep, dim3(576), blk, 0, stream, fuse_w, Whi, Wlo);
    hipLaunchKernelGGL(zero_feat, dim3(4), blk, 0, stream, feat);
    hipLaunchKernelGGL(fuse_mfma, dim3(8, 64), blk, 0, stream, Ahi, Alo, Whi, Wlo, fuse_b, feat);
    hipLaunchKernelGGL(det_nms, dim3(1), dim3(64), 0, stream, feat, det_w, det_b, out);
}